// Round 1
// baseline (20653.471 us; speedup 1.0000x reference)
//
#include <hip/hip_runtime.h>
#include <hip/hip_fp16.h>

// LSTM autoencoder: B=64, S=256, D=H=1024, L=2.
// Strategy (round 1): f16-input MFMA (fp32 accum) for all matmuls.
// One "phase" kernel per pipelined step: layer0 step t=p and layer1 step t=p-1
// run in the same launch (both depend only on phase p-1 outputs).
// 257 phases encoder + 257 phases decoder, all graph-captured.

#define Bsz 64
#define Ssz 256
#define Dh  1024
#define G4  4096

typedef _Float16 half8 __attribute__((ext_vector_type(8)));
typedef float    f32x4 __attribute__((ext_vector_type(4)));

__device__ __forceinline__ float sigm_(float x) { return 1.f / (1.f + __expf(-x)); }
__device__ __forceinline__ float tanhf_(float x) {
  // overflow-safe tanh via exp(-2|x|)
  float e = __expf(-2.f * fabsf(x));
  float r = (1.f - e) / (1.f + e);
  return x >= 0.f ? r : -r;
}

__global__ __launch_bounds__(256) void cvt_kernel(const float* __restrict__ src,
                                                  __half* __restrict__ dst, int n, int flip) {
  int i = blockIdx.x * 256 + threadIdx.x;
  if (i >= n) return;
  int idx = i;
  if (flip) { int k = i & (Dh - 1); idx = i - k + (Dh - 1 - k); }  // flip k within row of 1024
  dst[i] = __float2half(src[idx]);
}

__global__ void fail_mark(float* out) { out[0] = 1.0e9f; }  // sentinel: ws too small

// Grid: 128 blocks = (layer in {0,1}) x (64 j-strips of width 16). Block: 256 thr = 4 waves,
// wave w owns batch rows [16w,16w+16). Wave computes 4 gate n-tiles (i,f,g,o at n=q*1024+j)
// for its m-tile over K=1024 (input seg) + K=1024 (recurrent seg).
__global__ __launch_bounds__(256) void lstm_phase(
    const __half* __restrict__ A0, long long A0rs,          // layer0 input rows (x_t / emb)
    const __half* __restrict__ W0i, const __half* __restrict__ W0h,
    const float* __restrict__ b0i, const float* __restrict__ b0h,
    const __half* __restrict__ h0p, __half* __restrict__ h0n, float* __restrict__ c0,
    const __half* __restrict__ W1i, const __half* __restrict__ W1h,
    const float* __restrict__ b1i, const float* __restrict__ b1h,
    const __half* __restrict__ h1p, __half* __restrict__ h1n, float* __restrict__ c1,
    float* __restrict__ out, int mode, int t_out, int active0, int active1)
{
  const int layer = blockIdx.x >> 6;
  if (layer == 0) { if (!active0) return; } else { if (!active1) return; }
  const int j0   = (blockIdx.x & 63) << 4;
  const int lane = threadIdx.x & 63;
  const int brow = (threadIdx.x >> 6) << 4;   // wave's m-tile base (batch rows)
  const int arow = brow + (lane & 15);        // A-frag row for this lane
  const int koff = (lane >> 4) << 3;          // A/B-frag k offset (contiguous 8 f16)
  const int col  = lane & 15;                 // B-frag column / C col

  const __half *sA, *wA, *sB, *wB;
  const float *bi, *bh;
  __half* hn; float* cc;
  long long rsA;
  if (layer == 0) { sA = A0;  rsA = A0rs; wA = W0i; sB = h0p; wB = W0h; bi = b0i; bh = b0h; hn = h0n; cc = c0; }
  else            { sA = h0p; rsA = Dh;   wA = W1i; sB = h1p; wB = W1h; bi = b1i; bh = b1h; hn = h1n; cc = c1; }

  f32x4 acc0 = {0.f,0.f,0.f,0.f};
  f32x4 acc1 = {0.f,0.f,0.f,0.f};
  f32x4 acc2 = {0.f,0.f,0.f,0.f};
  f32x4 acc3 = {0.f,0.f,0.f,0.f};

  #pragma unroll
  for (int s = 0; s < 2; ++s) {
    const __half* a = (s == 0 ? sA + (long long)arow * rsA : sB + (long long)arow * Dh) + koff;
    const __half* w = (s == 0) ? wA : wB;
    const __half* bp0 = w + (long long)(j0 + col) * Dh + koff;
    const __half* bp1 = bp0 + (long long)1024 * Dh;
    const __half* bp2 = bp0 + (long long)2048 * Dh;
    const __half* bp3 = bp0 + (long long)3072 * Dh;
    #pragma unroll 4
    for (int ks = 0; ks < 32; ++ks) {
      half8 av  = *(const half8*)(a   + ks * 32);
      half8 b0v = *(const half8*)(bp0 + ks * 32);
      half8 b1v = *(const half8*)(bp1 + ks * 32);
      half8 b2v = *(const half8*)(bp2 + ks * 32);
      half8 b3v = *(const half8*)(bp3 + ks * 32);
      acc0 = __builtin_amdgcn_mfma_f32_16x16x32_f16(av, b0v, acc0, 0, 0, 0);
      acc1 = __builtin_amdgcn_mfma_f32_16x16x32_f16(av, b1v, acc1, 0, 0, 0);
      acc2 = __builtin_amdgcn_mfma_f32_16x16x32_f16(av, b2v, acc2, 0, 0, 0);
      ac3:
      acc3 = __builtin_amdgcn_mfma_f32_16x16x32_f16(av, b3v, acc3, 0, 0, 0);
    }
  }

  // Epilogue: lane holds gates (i,f,g,o) for 4 (b, j) pairs; fully in-register LSTM cell.
  const int j = j0 + col;
  const float bsi = bi[j]        + bh[j];
  const float bsf = bi[Dh + j]   + bh[Dh + j];
  const float bsg = bi[2*Dh + j] + bh[2*Dh + j];
  const float bso = bi[3*Dh + j] + bh[3*Dh + j];
  #pragma unroll
  for (int r = 0; r < 4; ++r) {
    const int b = brow + ((lane >> 4) << 2) + r;     // C/D row mapping (m89)
    const float gi = acc0[r] + bsi;
    const float gf = acc1[r] + bsf;
    const float gg = acc2[r] + bsg;
    const float go = acc3[r] + bso;
    const float iv = sigm_(gi), fv = sigm_(gf), gv = tanhf_(gg), ov = sigm_(go);
    const long long ci = (long long)b * Dh + j;
    const float cn = fv * cc[ci] + iv * gv;
    cc[ci] = cn;
    const float h = ov * tanhf_(cn);
    hn[ci] = __float2half(h);
    if (layer == 1) {
      if (mode == 1)      out[ci] = h;                                             // emb
      else if (mode == 2) out[(long long)65536 + ((long long)b * Ssz + t_out) * Dh + (Dh - 1 - j)] = h;  // decoded (feature flip)
    }
  }
}

extern "C" void kernel_launch(void* const* d_in, const int* in_sizes, int n_in,
                              void* d_out, int out_size, void* d_ws, size_t ws_size,
                              hipStream_t stream) {
  const float* x     = (const float*)d_in[0];
  const float* eWih0 = (const float*)d_in[1];
  const float* eWhh0 = (const float*)d_in[2];
  const float* ebih0 = (const float*)d_in[3];
  const float* ebhh0 = (const float*)d_in[4];
  const float* eWih1 = (const float*)d_in[5];
  const float* eWhh1 = (const float*)d_in[6];
  const float* ebih1 = (const float*)d_in[7];
  const float* ebhh1 = (const float*)d_in[8];
  const float* dWih0 = (const float*)d_in[9];
  const float* dWhh0 = (const float*)d_in[10];
  const float* dbih0 = (const float*)d_in[11];
  const float* dbhh0 = (const float*)d_in[12];
  const float* dWih1 = (const float*)d_in[13];
  const float* dWhh1 = (const float*)d_in[14];
  const float* dbih1 = (const float*)d_in[15];
  const float* dbhh1 = (const float*)d_in[16];
  float* out = (float*)d_out;

  const size_t WSZ = (size_t)G4 * Dh;                 // 4M elements per weight matrix
  const size_t WB  = WSZ * sizeof(__half);            // 8 MB
  char* ws = (char*)d_ws;
  size_t off = 0;
  auto alloc = [&](size_t bytes) { char* p = ws + off; off += (bytes + 255) & ~(size_t)255; return p; };
  __half* wE0i  = (__half*)alloc(WB);
  __half* wE0h  = (__half*)alloc(WB);
  __half* wE1i  = (__half*)alloc(WB);
  __half* wE1h  = (__half*)alloc(WB);
  __half* wD0i  = (__half*)alloc(WB);    // unflipped (for emb input at dec t=0)
  __half* wD0if = (__half*)alloc(WB);    // k-flipped (consumes flipped_x via plain x)
  __half* wD0h  = (__half*)alloc(WB);
  __half* wD1i  = (__half*)alloc(WB);
  __half* wD1h  = (__half*)alloc(WB);
  __half* xf16  = (__half*)alloc((size_t)Bsz * Ssz * Dh * sizeof(__half));
  __half* h0b0  = (__half*)alloc((size_t)Bsz * Dh * sizeof(__half));
  __half* h0b1  = (__half*)alloc((size_t)Bsz * Dh * sizeof(__half));
  __half* h1b0  = (__half*)alloc((size_t)Bsz * Dh * sizeof(__half));
  __half* h1b1  = (__half*)alloc((size_t)Bsz * Dh * sizeof(__half));
  float*  c0    = (float*)alloc((size_t)Bsz * Dh * sizeof(float));
  float*  c1    = (float*)alloc((size_t)Bsz * Dh * sizeof(float));
  __half* h0b[2] = {h0b0, h0b1};
  __half* h1b[2] = {h1b0, h1b1};

  if (ws_size < off) {  // not enough scratch: leave distinctive sentinel and bail
    hipLaunchKernelGGL(fail_mark, dim3(1), dim3(1), 0, stream, out);
    return;
  }

  // f16 weight/x conversions (every call; deterministic)
  const int wgrid = (int)((WSZ + 255) / 256);
  cvt_kernel<<<wgrid, 256, 0, stream>>>(eWih0, wE0i, (int)WSZ, 0);
  cvt_kernel<<<wgrid, 256, 0, stream>>>(eWhh0, wE0h, (int)WSZ, 0);
  cvt_kernel<<<wgrid, 256, 0, stream>>>(eWih1, wE1i, (int)WSZ, 0);
  cvt_kernel<<<wgrid, 256, 0, stream>>>(eWhh1, wE1h, (int)WSZ, 0);
  cvt_kernel<<<wgrid, 256, 0, stream>>>(dWih0, wD0i, (int)WSZ, 0);
  cvt_kernel<<<wgrid, 256, 0, stream>>>(dWih0, wD0if, (int)WSZ, 1);
  cvt_kernel<<<wgrid, 256, 0, stream>>>(dWhh0, wD0h, (int)WSZ, 0);
  cvt_kernel<<<wgrid, 256, 0, stream>>>(dWih1, wD1i, (int)WSZ, 0);
  cvt_kernel<<<wgrid, 256, 0, stream>>>(dWhh1, wD1h, (int)WSZ, 0);
  const int xn = Bsz * Ssz * Dh;
  cvt_kernel<<<(xn + 255) / 256, 256, 0, stream>>>(x, xf16, xn, 0);

  // zero initial states (graph-captured; runs every replay)
  hipMemsetAsync(h0b0, 0, (size_t)Bsz * Dh * 2, stream);
  hipMemsetAsync(h0b1, 0, (size_t)Bsz * Dh * 2, stream);
  hipMemsetAsync(h1b0, 0, (size_t)Bsz * Dh * 2, stream);
  hipMemsetAsync(h1b1, 0, (size_t)Bsz * Dh * 2, stream);
  hipMemsetAsync(c0, 0, (size_t)Bsz * Dh * 4, stream);
  hipMemsetAsync(c1, 0, (size_t)Bsz * Dh * 4, stream);

  int cur0 = 0, cur1 = 0;
  for (int P = 0; P < 2 * (Ssz + 1); ++P) {
    const int dec = P >= (Ssz + 1);
    const int p = dec ? P - (Ssz + 1) : P;
    const int active0 = (p <= Ssz - 1);
    const int active1 = (p >= 1);
    const int t0 = p, t1 = p - 1;

    const __half* A0; long long rs;
    const __half *W0i_, *W0h_, *W1i_, *W1h_;
    const float *bi0, *bh0, *bi1, *bh1;
    if (!dec) {
      A0 = xf16 + (size_t)t0 * Dh; rs = (long long)Ssz * Dh;
      W0i_ = wE0i; W0h_ = wE0h; W1i_ = wE1i; W1h_ = wE1h;
      bi0 = ebih0; bh0 = ebhh0; bi1 = ebih1; bh1 = ebhh1;
    } else {
      W0h_ = wD0h; W1i_ = wD1i; W1h_ = wD1h;
      bi0 = dbih0; bh0 = dbhh0; bi1 = dbih1; bh1 = dbhh1;
      if (t0 == 0) { A0 = h1b[cur1]; rs = Dh; W0i_ = wD0i; }          // input = emb
      else { A0 = xf16 + (size_t)(t0 - 1) * Dh; rs = (long long)Ssz * Dh; W0i_ = wD0if; }
    }

    int mode = 0, tout = 0;
    if (!dec && p == Ssz) mode = 1;            // layer1 computes t=255 -> emb
    if (dec && active1) { mode = 2; tout = t1; }

    lstm_phase<<<128, 256, 0, stream>>>(
        A0, rs, W0i_, W0h_, bi0, bh0, h0b[cur0], h0b[cur0 ^ 1], c0,
        W1i_, W1h_, bi1, bh1, h1b[cur1], h1b[cur1 ^ 1], c1,
        out, mode, tout, active0, active1);

    if (active0) cur0 ^= 1;
    if (active1) cur1 ^= 1;
  }
}